// Round 1
// baseline (327.310 us; speedup 1.0000x reference)
//
#include <hip/hip_runtime.h>
#include <stdint.h>

typedef __attribute__((ext_vector_type(8))) short bf16x8;
typedef __attribute__((ext_vector_type(4))) float f32x4;
typedef __attribute__((ext_vector_type(8))) unsigned short u16x8;
typedef __attribute__((ext_vector_type(4))) unsigned short u16x4;

#define MFMA16(a, b, c) __builtin_amdgcn_mfma_f32_16x16x32_bf16((a), (b), (c), 0, 0, 0)

static __device__ __forceinline__ unsigned short f2bf(float x) {
  unsigned int u = __builtin_bit_cast(unsigned int, x);
  u += 0x7fff + ((u >> 16) & 1);   // RNE
  return (unsigned short)(u >> 16);
}

// ---------------------------------------------------------------- convert f32 -> bf16
__global__ __launch_bounds__(256) void cvt_bf16(const float* __restrict__ in,
                                                unsigned short* __restrict__ out) {
  const size_t i = (size_t)(blockIdx.x * 256 + threadIdx.x) * 8;
  f32x4 a = *(const f32x4*)(in + i);
  f32x4 b = *(const f32x4*)(in + i + 4);
  u16x8 o;
  o[0] = f2bf(a[0]); o[1] = f2bf(a[1]); o[2] = f2bf(a[2]); o[3] = f2bf(a[3]);
  o[4] = f2bf(b[0]); o[5] = f2bf(b[1]); o[6] = f2bf(b[2]); o[7] = f2bf(b[3]);
  *(u16x8*)(out + i) = o;
}

// ---------------------------------------------------------------- RoPE table [L][32] (cos, sin)
__global__ __launch_bounds__(256) void rope_table_k(float2* __restrict__ tab) {
  const int i = blockIdx.x * 256 + threadIdx.x;   // 0 .. 65535
  const int l = i >> 5, f = i & 31;
  float inv = powf(10000.0f, -(float)f / 32.0f);
  float ang = (float)l * inv;
  float s, c;
  sincosf(ang, &s, &c);
  tab[i] = make_float2(c, s);
}

// ---------------------------------------------------------------- GEMM: C = A[M,K] * W[N,K]^T + bias
// EPI 0: f32 plain output [M][1024]
// EPI 1: RoPE + scale, bf16 scatter to [B,H,L,64]
// EPI 2: bf16 scatter to [B,H,L,64] (no rope)
template <int EPI>
__global__ __launch_bounds__(256)
void gemm_bt(const unsigned short* __restrict__ Am,
             const unsigned short* __restrict__ Wm,
             const float* __restrict__ bias,
             void* __restrict__ outp,
             const float2* __restrict__ rope,
             float scale) {
  constexpr int K = 1024;
  __shared__ unsigned short As[128 * 64];
  __shared__ unsigned short Bs[128 * 64];
  const int t = threadIdx.x;
  const int lane = t & 63, w = t >> 6;
  const int lq = lane & 15, lg = lane >> 4;
  const int wr = w >> 1, wc = w & 1;
  const int row0 = blockIdx.y * 128;
  const int col0 = blockIdx.x * 128;

  f32x4 acc[4][4] = {};

  for (int kt = 0; kt < K / 64; ++kt) {
    __syncthreads();
#pragma unroll
    for (int it = 0; it < 4; ++it) {
      const int s = it * 256 + t;                 // slot 0..1023, row = s>>3, chunk = s&7
      const int ldsoff = (it * 256 + w * 64) * 8; // wave-uniform base (shorts)
      {
        const unsigned short* g = Am + (size_t)(row0 + (s >> 3)) * K + kt * 64 + (s & 7) * 8;
        __builtin_amdgcn_global_load_lds((const __attribute__((address_space(1))) void*)g,
                                         (__attribute__((address_space(3))) void*)(As + ldsoff),
                                         16, 0, 0);
      }
      {
        const unsigned short* g = Wm + (size_t)(col0 + (s >> 3)) * K + kt * 64 + (s & 7) * 8;
        __builtin_amdgcn_global_load_lds((const __attribute__((address_space(1))) void*)g,
                                         (__attribute__((address_space(3))) void*)(Bs + ldsoff),
                                         16, 0, 0);
      }
    }
    __syncthreads();
#pragma unroll
    for (int kc = 0; kc < 2; ++kc) {
      bf16x8 af[4], bfr[4];
#pragma unroll
      for (int mf = 0; mf < 4; ++mf)
        af[mf] = *(const bf16x8*)(As + (wr * 64 + mf * 16 + lq) * 64 + kc * 32 + lg * 8);
#pragma unroll
      for (int nf = 0; nf < 4; ++nf)
        bfr[nf] = *(const bf16x8*)(Bs + (wc * 64 + nf * 16 + lq) * 64 + kc * 32 + lg * 8);
#pragma unroll
      for (int mf = 0; mf < 4; ++mf)
#pragma unroll
        for (int nf = 0; nf < 4; ++nf)
          acc[mf][nf] = MFMA16(af[mf], bfr[nf], acc[mf][nf]);
    }
  }

  // epilogue
#pragma unroll
  for (int mf = 0; mf < 4; ++mf) {
#pragma unroll
    for (int nf = 0; nf < 4; ++nf) {
      const int col = col0 + wc * 64 + nf * 16 + lq;
      const float bv = bias[col];
      if constexpr (EPI == 0) {
        float* o = (float*)outp;
#pragma unroll
        for (int i = 0; i < 4; ++i) {
          const int row = row0 + wr * 64 + mf * 16 + 4 * lg + i;
          o[(size_t)row * 1024 + col] = acc[mf][nf][i] + bv;
        }
      } else {
        unsigned short* o = (unsigned short*)outp;
        const int h = col >> 6, d = col & 63;
#pragma unroll
        for (int i = 0; i < 4; ++i) {
          const int row = row0 + wr * 64 + mf * 16 + 4 * lg + i;
          const int b = row >> 11, l = row & 2047;
          float val = acc[mf][nf][i] + bv;
          if constexpr (EPI == 1) {
            float2 cs = rope[l * 32 + (d >> 1)];
            float p = __shfl_xor(val, 1, 64);
            val = ((d & 1) ? (val * cs.x + p * cs.y) : (val * cs.x - p * cs.y)) * scale;
          }
          o[(((size_t)b * 16 + h) * 2048 + l) * 64 + d] = f2bf(val);
        }
      }
    }
  }
}

// ---------------------------------------------------------------- Vh [bh][L][64] -> VhT [bh][64][L]
__global__ __launch_bounds__(256) void transpose_v(const unsigned short* __restrict__ Vh,
                                                   unsigned short* __restrict__ VhT) {
  __shared__ unsigned short tile[64][72];
  const int bh = blockIdx.y;
  const int lb = blockIdx.x * 64;
  const int t = threadIdx.x;
  {
    const int l = t >> 2, c = t & 3;  // 64 rows x 4 chunks of 16 shorts? no: chunk = 16B = 8 shorts; row=64 shorts -> 8 chunks
  }
  // 512 slots of 8 shorts: two iterations
#pragma unroll
  for (int it = 0; it < 2; ++it) {
    const int s = it * 256 + t;
    const int l = s >> 3, c = s & 7;
    bf16x8 v = *(const bf16x8*)(Vh + ((size_t)bh * 2048 + lb + l) * 64 + c * 8);
    *(bf16x8*)(&tile[l][c * 8]) = v;
  }
  __syncthreads();
#pragma unroll
  for (int it = 0; it < 2; ++it) {
    const int s = it * 256 + t;
    const int d = s >> 3, c = s & 7;
    u16x8 o;
#pragma unroll
    for (int j = 0; j < 8; ++j) o[j] = tile[c * 8 + j][d];
    *(u16x8*)(VhT + ((size_t)bh * 64 + d) * 2048 + lb + c * 8) = o;
  }
}

// ---------------------------------------------------------------- flash attention (causal)
// Qh [bh][L][64] (pre-scaled by 1/8), Kh [bh][L][64], VhT [bh][64][L]
// out attn [B][L][1024] bf16 at ((b*L + l)*1024 + h*64 + d)
__global__ __launch_bounds__(256)
void attn_fwd(const unsigned short* __restrict__ Qh,
              const unsigned short* __restrict__ Kh,
              const unsigned short* __restrict__ VhT,
              unsigned short* __restrict__ attn) {
  constexpr int L = 2048;
  __shared__ unsigned short Kl[64 * 64];      // XOR-swizzled [kv][d]
  __shared__ unsigned short Vt[64 * 64];      // XOR-swizzled [d][kv]
  __shared__ unsigned short Pl[4][16 * 72];   // per-wave P [q][kv], +8 pad
  const int t = threadIdx.x;
  const int lane = t & 63, w = t >> 6;
  const int lq = lane & 15, lg = lane >> 4;
  const int bh = blockIdx.y;
  const int qb = blockIdx.x * 64;
  const int qw = qb + w * 16;
  const int qrow = qw + lq;

  // Q fragments (B-operand layout): lane holds Q[qrow][kc*32 + lg*8 .. +8]
  bf16x8 qf[2];
  {
    const unsigned short* qp = Qh + ((size_t)bh * L + qrow) * 64;
    qf[0] = *(const bf16x8*)(qp + lg * 8);
    qf[1] = *(const bf16x8*)(qp + 32 + lg * 8);
  }

  float m = -1e30f, lsum = 0.0f;
  f32x4 ot[4] = {};   // O^T frags: d = df*16 + 4*lg + i, q = lq

  char* const pw = (char*)&Pl[w][0];
  const int nkv = blockIdx.x + 1;

  for (int kb = 0; kb < nkv; ++kb) {
    const int kv0 = kb * 64;
    __syncthreads();
    // stage K tile [64][64] swizzled: byte ^= (row&7)<<4
#pragma unroll
    for (int it = 0; it < 2; ++it) {
      const int s = it * 256 + t;
      const int r = s >> 3, c = s & 7;
      bf16x8 v = *(const bf16x8*)(Kh + ((size_t)bh * L + kv0 + r) * 64 + c * 8);
      int byte = r * 128 + c * 16;
      byte ^= (r & 7) << 4;
      *(bf16x8*)((char*)Kl + byte) = v;
    }
    // stage V^T tile [64 d][64 kv] swizzled
#pragma unroll
    for (int it = 0; it < 2; ++it) {
      const int s = it * 256 + t;
      const int d = s >> 3, c = s & 7;
      bf16x8 v = *(const bf16x8*)(VhT + ((size_t)bh * 64 + d) * L + kv0 + c * 8);
      int byte = d * 128 + c * 16;
      byte ^= (d & 7) << 4;
      *(bf16x8*)((char*)Vt + byte) = v;
    }
    __syncthreads();

    // S^T[kv][q] = K . Q^T   (4 kv-frags x 2 k-chunks)
    f32x4 st[4];
#pragma unroll
    for (int kf = 0; kf < 4; ++kf) {
      f32x4 c = {};
#pragma unroll
      for (int kc = 0; kc < 2; ++kc) {
        const int r = kf * 16 + lq;
        int byte = r * 128 + kc * 64 + lg * 16;
        byte ^= (r & 7) << 4;
        bf16x8 kfr = *(const bf16x8*)((char*)Kl + byte);
        c = MFMA16(kfr, qf[kc], c);
      }
      st[kf] = c;
    }

    // causal mask (only the diagonal block needs it)
    if (kb == nkv - 1) {
#pragma unroll
      for (int kf = 0; kf < 4; ++kf)
#pragma unroll
        for (int i = 0; i < 4; ++i) {
          const int kv = kv0 + kf * 16 + 4 * lg + i;
          if (kv > qrow) st[kf][i] = -1e30f;
        }
    }

    // online softmax over kv (per q = lq)
    float pmax = -1e30f;
#pragma unroll
    for (int kf = 0; kf < 4; ++kf)
#pragma unroll
      for (int i = 0; i < 4; ++i) pmax = fmaxf(pmax, st[kf][i]);
    pmax = fmaxf(pmax, __shfl_xor(pmax, 16, 64));
    pmax = fmaxf(pmax, __shfl_xor(pmax, 32, 64));
    const float mnew = fmaxf(m, pmax);
    const float corr = __expf(m - mnew);

    float psum = 0.0f;
#pragma unroll
    for (int kf = 0; kf < 4; ++kf) {
      float p0 = __expf(st[kf][0] - mnew);
      float p1 = __expf(st[kf][1] - mnew);
      float p2 = __expf(st[kf][2] - mnew);
      float p3 = __expf(st[kf][3] - mnew);
      psum += (p0 + p1) + (p2 + p3);
      unsigned int k0 = (unsigned int)f2bf(p0) | ((unsigned int)f2bf(p1) << 16);
      unsigned int k1 = (unsigned int)f2bf(p2) | ((unsigned int)f2bf(p3) << 16);
      // P[q=lq][kv = kf*16 + 4*lg + i]
      unsigned int* dst = (unsigned int*)(pw + lq * 144 + kf * 32 + lg * 8);
      dst[0] = k0;
      dst[1] = k1;
    }
    psum += __shfl_xor(psum, 16, 64);
    psum += __shfl_xor(psum, 32, 64);
    lsum = lsum * corr + psum;
    m = mnew;
#pragma unroll
    for (int df = 0; df < 4; ++df)
#pragma unroll
      for (int i = 0; i < 4; ++i) ot[df][i] *= corr;

    // make this wave's P writes visible to its own ds_reads
    asm volatile("s_waitcnt lgkmcnt(0)" ::: "memory");

    // O^T[d][q] += V^T . P^T
#pragma unroll
    for (int df = 0; df < 4; ++df) {
#pragma unroll
      for (int kc = 0; kc < 2; ++kc) {
        const int r = df * 16 + lq;
        int byte = r * 128 + kc * 64 + lg * 16;
        byte ^= (r & 7) << 4;
        bf16x8 vf = *(const bf16x8*)((char*)Vt + byte);
        bf16x8 pf = *(const bf16x8*)(pw + lq * 144 + kc * 64 + lg * 16);
        ot[df] = MFMA16(vf, pf, ot[df]);
      }
    }
  }

  // finalize + store
  const float inv = 1.0f / lsum;
  const int b = bh >> 4, h = bh & 15;
#pragma unroll
  for (int df = 0; df < 4; ++df) {
    u16x4 o;
#pragma unroll
    for (int i = 0; i < 4; ++i) o[i] = f2bf(ot[df][i] * inv);
    const int d = df * 16 + 4 * lg;
    *(u16x4*)(attn + ((size_t)b * L + qrow) * 1024 + h * 64 + d) = o;
  }
}

// ---------------------------------------------------------------- launcher
extern "C" void kernel_launch(void* const* d_in, const int* in_sizes, int n_in,
                              void* d_out, int out_size, void* d_ws, size_t ws_size,
                              hipStream_t stream) {
  const float* q  = (const float*)d_in[0];
  const float* k  = (const float*)d_in[1];
  const float* v  = (const float*)d_in[2];
  const float* Wq = (const float*)d_in[3];
  const float* bq = (const float*)d_in[4];
  const float* Wk = (const float*)d_in[5];
  const float* bk = (const float*)d_in[6];
  const float* Wv = (const float*)d_in[7];
  const float* bv = (const float*)d_in[8];
  const float* Wo = (const float*)d_in[9];
  const float* bo = (const float*)d_in[10];

  char* ws = (char*)d_ws;
  const size_t MB = 1ull << 20;
  unsigned short* qb  = (unsigned short*)(ws + 0 * MB);    // 16MB  (later reused as attn)
  unsigned short* kb  = (unsigned short*)(ws + 16 * MB);   // 16MB  (later reused as VhT)
  unsigned short* vb  = (unsigned short*)(ws + 32 * MB);   // 16MB
  unsigned short* Wqb = (unsigned short*)(ws + 48 * MB);   // 2MB
  unsigned short* Wkb = (unsigned short*)(ws + 50 * MB);   // 2MB
  unsigned short* Wvb = (unsigned short*)(ws + 52 * MB);   // 2MB
  unsigned short* Wob = (unsigned short*)(ws + 54 * MB);   // 2MB
  float2*        rope = (float2*)(ws + 56 * MB);           // 512KB
  unsigned short* Qh  = (unsigned short*)(ws + 57 * MB);   // 16MB
  unsigned short* Kh  = (unsigned short*)(ws + 73 * MB);   // 16MB
  unsigned short* Vh  = (unsigned short*)(ws + 89 * MB);   // 16MB  (total 105MB)
  unsigned short* VhT = kb;    // alias: kb dead after K projection
  unsigned short* attnb = qb;  // alias: qb dead after Q projection

  // 1. convert to bf16
  cvt_bf16<<<4096, 256, 0, stream>>>(q, qb);
  cvt_bf16<<<4096, 256, 0, stream>>>(k, kb);
  cvt_bf16<<<4096, 256, 0, stream>>>(v, vb);
  cvt_bf16<<<512, 256, 0, stream>>>(Wq, Wqb);
  cvt_bf16<<<512, 256, 0, stream>>>(Wk, Wkb);
  cvt_bf16<<<512, 256, 0, stream>>>(Wv, Wvb);
  cvt_bf16<<<512, 256, 0, stream>>>(Wo, Wob);

  // 2. rope table
  rope_table_k<<<256, 256, 0, stream>>>(rope);

  // 3. projections (+bias, +rope, Q pre-scaled by 1/sqrt(64))
  dim3 gg(8, 64);
  gemm_bt<1><<<gg, 256, 0, stream>>>(qb, Wqb, bq, Qh, rope, 0.125f);
  gemm_bt<1><<<gg, 256, 0, stream>>>(kb, Wkb, bk, Kh, rope, 1.0f);
  gemm_bt<2><<<gg, 256, 0, stream>>>(vb, Wvb, bv, Vh, rope, 1.0f);

  // 4. V transpose for PV step
  transpose_v<<<dim3(32, 64), 256, 0, stream>>>(Vh, VhT);

  // 5. causal flash attention
  attn_fwd<<<dim3(32, 64), 256, 0, stream>>>(Qh, Kh, VhT, attnb);

  // 6. output projection -> f32
  gemm_bt<0><<<gg, 256, 0, stream>>>(attnb, Wob, bo, d_out, rope, 1.0f);

  (void)in_sizes; (void)n_in; (void)out_size; (void)ws_size;
}

// Round 2
// 265.566 us; speedup vs baseline: 1.2325x; 1.2325x over previous
//
#include <hip/hip_runtime.h>
#include <stdint.h>

typedef __attribute__((ext_vector_type(8))) short bf16x8;
typedef __attribute__((ext_vector_type(4))) float f32x4;
typedef __attribute__((ext_vector_type(8))) unsigned short u16x8;
typedef __attribute__((ext_vector_type(4))) unsigned short u16x4;
typedef unsigned short ushort_t;

#define MFMA16(a, b, c) __builtin_amdgcn_mfma_f32_16x16x32_bf16((a), (b), (c), 0, 0, 0)
#define GLDS(g, l)                                                              \
  __builtin_amdgcn_global_load_lds((const __attribute__((address_space(1))) void*)(g), \
                                   (__attribute__((address_space(3))) void*)(l), 16, 0, 0)

static __device__ __forceinline__ unsigned short f2bf(float x) {
  unsigned int u = __builtin_bit_cast(unsigned int, x);
  u += 0x7fff + ((u >> 16) & 1);  // RNE
  return (unsigned short)(u >> 16);
}

static __device__ __forceinline__ unsigned cvtpk_bf16(float lo, float hi) {
  unsigned r;
  asm("v_cvt_pk_bf16_f32 %0, %1, %2" : "=v"(r) : "v"(lo), "v"(hi));
  return r;
}

// ---------------------------------------------------------------- converts
__global__ __launch_bounds__(256) void cvt_qkv(const float* __restrict__ q,
                                               const float* __restrict__ k,
                                               const float* __restrict__ v,
                                               ushort_t* __restrict__ oq,
                                               ushort_t* __restrict__ ok,
                                               ushort_t* __restrict__ ov) {
  const float* in = blockIdx.y == 0 ? q : (blockIdx.y == 1 ? k : v);
  ushort_t* out = blockIdx.y == 0 ? oq : (blockIdx.y == 1 ? ok : ov);
  const size_t i = (size_t)(blockIdx.x * 256 + threadIdx.x) * 8;
  f32x4 a = *(const f32x4*)(in + i);
  f32x4 b = *(const f32x4*)(in + i + 4);
  u16x8 o;
  o[0] = f2bf(a[0]); o[1] = f2bf(a[1]); o[2] = f2bf(a[2]); o[3] = f2bf(a[3]);
  o[4] = f2bf(b[0]); o[5] = f2bf(b[1]); o[6] = f2bf(b[2]); o[7] = f2bf(b[3]);
  *(u16x8*)(out + i) = o;
}

__global__ __launch_bounds__(256) void cvt_w(const float* __restrict__ w0,
                                             const float* __restrict__ w1,
                                             const float* __restrict__ w2,
                                             const float* __restrict__ w3,
                                             ushort_t* __restrict__ o0,
                                             ushort_t* __restrict__ o1,
                                             ushort_t* __restrict__ o2,
                                             ushort_t* __restrict__ o3) {
  const float* in = blockIdx.y == 0 ? w0 : (blockIdx.y == 1 ? w1 : (blockIdx.y == 2 ? w2 : w3));
  ushort_t* out = blockIdx.y == 0 ? o0 : (blockIdx.y == 1 ? o1 : (blockIdx.y == 2 ? o2 : o3));
  const size_t i = (size_t)(blockIdx.x * 256 + threadIdx.x) * 8;
  f32x4 a = *(const f32x4*)(in + i);
  f32x4 b = *(const f32x4*)(in + i + 4);
  u16x8 o;
  o[0] = f2bf(a[0]); o[1] = f2bf(a[1]); o[2] = f2bf(a[2]); o[3] = f2bf(a[3]);
  o[4] = f2bf(b[0]); o[5] = f2bf(b[1]); o[6] = f2bf(b[2]); o[7] = f2bf(b[3]);
  *(u16x8*)(out + i) = o;
}

// ---------------------------------------------------------------- RoPE table [L][32] (cos, sin)
__global__ __launch_bounds__(256) void rope_table_k(float2* __restrict__ tab) {
  const int i = blockIdx.x * 256 + threadIdx.x;  // 0 .. 65535
  const int l = i >> 5, f = i & 31;
  float inv = powf(10000.0f, -(float)f / 32.0f);
  float ang = (float)l * inv;
  float s, c;
  sincosf(ang, &s, &c);
  tab[i] = make_float2(c, s);
}

// ---------------------------------------------------------------- GEMM: C = A[M,K] * W[N,K]^T + bias
// EPI 0: f32 plain output [M][1024]
// EPI 1: RoPE + scale, bf16 scatter to [B,H,L,64]
// EPI 2: bf16 scatter to [B,H,L,64] (no rope)
template <int EPI>
__global__ __launch_bounds__(256)
void gemm_bt(const ushort_t* __restrict__ Am, const ushort_t* __restrict__ Wm,
             const float* __restrict__ bias, void* __restrict__ outp,
             const float2* __restrict__ rope, float scale) {
  constexpr int K = 1024;
  __shared__ ushort_t As[2][128 * 64];
  __shared__ ushort_t Bs[2][128 * 64];
  const int t = threadIdx.x;
  const int lane = t & 63, w = t >> 6;
  const int lq = lane & 15, lg = lane >> 4;
  const int wr = w >> 1, wc = w & 1;
  const int row0 = blockIdx.y * 128;
  const int col0 = blockIdx.x * 128;

  auto STG = [&](int bb, int kt) {
#pragma unroll
    for (int it = 0; it < 4; ++it) {
      const int s = it * 256 + t;
      const int ldsoff = (it * 256 + w * 64) * 8;
      GLDS(Am + (size_t)(row0 + (s >> 3)) * K + kt * 64 + (s & 7) * 8, &As[bb][ldsoff]);
      GLDS(Wm + (size_t)(col0 + (s >> 3)) * K + kt * 64 + (s & 7) * 8, &Bs[bb][ldsoff]);
    }
  };

  f32x4 acc[4][4] = {};
  STG(0, 0);
  __syncthreads();
  int cur = 0;
  for (int kt = 0; kt < K / 64; ++kt) {
    if (kt + 1 < K / 64) STG(cur ^ 1, kt + 1);  // prefetch overlaps compute (T3 min-recipe)
#pragma unroll
    for (int kc = 0; kc < 2; ++kc) {
      bf16x8 af[4], bfr[4];
#pragma unroll
      for (int mf = 0; mf < 4; ++mf)
        af[mf] = *(const bf16x8*)(&As[cur][(wr * 64 + mf * 16 + lq) * 64 + kc * 32 + lg * 8]);
#pragma unroll
      for (int nf = 0; nf < 4; ++nf)
        bfr[nf] = *(const bf16x8*)(&Bs[cur][(wc * 64 + nf * 16 + lq) * 64 + kc * 32 + lg * 8]);
#pragma unroll
      for (int mf = 0; mf < 4; ++mf)
#pragma unroll
        for (int nf = 0; nf < 4; ++nf)
          acc[mf][nf] = MFMA16(af[mf], bfr[nf], acc[mf][nf]);
    }
    __syncthreads();
    cur ^= 1;
  }

  // epilogue
#pragma unroll
  for (int mf = 0; mf < 4; ++mf) {
#pragma unroll
    for (int nf = 0; nf < 4; ++nf) {
      const int col = col0 + wc * 64 + nf * 16 + lq;
      const float bv = bias[col];
      if constexpr (EPI == 0) {
        float* o = (float*)outp;
#pragma unroll
        for (int u = 0; u < 4; ++u) {
          const int row = row0 + wr * 64 + mf * 16 + 4 * lg + u;
          o[(size_t)row * 1024 + col] = acc[mf][nf][u] + bv;
        }
      } else {
        ushort_t* o = (ushort_t*)outp;
        const int h = col >> 6, d = col & 63;
#pragma unroll
        for (int u = 0; u < 4; ++u) {
          const int row = row0 + wr * 64 + mf * 16 + 4 * lg + u;
          const int b = row >> 11, l = row & 2047;
          float val = acc[mf][nf][u] + bv;
          if constexpr (EPI == 1) {
            float2 cs = rope[l * 32 + (d >> 1)];
            float p = __shfl_xor(val, 1, 64);
            val = ((d & 1) ? (val * cs.x + p * cs.y) : (val * cs.x - p * cs.y)) * scale;
          }
          o[(((size_t)b * 16 + h) * 2048 + l) * 64 + d] = f2bf(val);
        }
      }
    }
  }
}

// ---------------------------------------------------------------- Vh [bh][L][64] -> VhT [bh][64][L]
__global__ __launch_bounds__(256) void transpose_v(const ushort_t* __restrict__ Vh,
                                                   ushort_t* __restrict__ VhT) {
  __shared__ ushort_t tile[64][72];
  const int bh = blockIdx.y;
  const int lb = blockIdx.x * 64;
  const int t = threadIdx.x;
#pragma unroll
  for (int it = 0; it < 2; ++it) {
    const int s = it * 256 + t;
    const int l = s >> 3, c = s & 7;
    bf16x8 v = *(const bf16x8*)(Vh + ((size_t)bh * 2048 + lb + l) * 64 + c * 8);
    *(bf16x8*)(&tile[l][c * 8]) = v;
  }
  __syncthreads();
#pragma unroll
  for (int it = 0; it < 2; ++it) {
    const int s = it * 256 + t;
    const int d = s >> 3, c = s & 7;
    u16x8 o;
#pragma unroll
    for (int j = 0; j < 8; ++j) o[j] = tile[c * 8 + j][d];
    *(u16x8*)(VhT + ((size_t)bh * 64 + d) * 2048 + lb + c * 8) = o;
  }
}

// ---------------------------------------------------------------- flash attention (causal)
// Work-balanced: block handles q-tiles (i, 31-i) sharing K/V staging -> 33 MFMA-tiles/block uniform.
// K/V double-buffered via global_load_lds (source pre-swizzled, read XOR-swizzled).
__global__ __launch_bounds__(256, 4)
void attn_fwd(const ushort_t* __restrict__ Qh, const ushort_t* __restrict__ Kh,
              const ushort_t* __restrict__ VhT, ushort_t* __restrict__ attn) {
  constexpr int L = 2048;
  __shared__ __align__(16) char KV[2][16384];  // [buf][ K 8KB | V^T 8KB ], XOR-swizzled
  __shared__ __align__(16) char Pl[4][2048];   // per-wave P [16 q][64 kv] bf16, XOR-swizzled
  const int t = threadIdx.x;
  const int lane = t & 63, w = t >> 6;
  const int lq = lane & 15, lg = lane >> 4;

  // XCD swizzle: all 16 blocks of one bh land on one XCD (K/V L2 reuse)
  const int fid = blockIdx.y * 16 + blockIdx.x;  // 0..1023
  const int bh = (fid & 7) * 8 + (fid >> 7);
  const int i = (fid >> 3) & 15;
  const int lo = i, hi = 31 - i, nt = 32 - i;
  const int qlo = lo * 64 + w * 16 + lq;
  const int qhi = hi * 64 + w * 16 + lq;

  bf16x8 qfl[2], qfh[2];
  {
    const ushort_t* p = Qh + ((size_t)bh * L + qlo) * 64 + lg * 8;
    qfl[0] = *(const bf16x8*)p;
    qfl[1] = *(const bf16x8*)(p + 32);
    const ushort_t* p2 = Qh + ((size_t)bh * L + qhi) * 64 + lg * 8;
    qfh[0] = *(const bf16x8*)p2;
    qfh[1] = *(const bf16x8*)(p2 + 32);
  }

  float ml = -1e30f, ll = 0.0f, mh = -1e30f, lh = 0.0f;
  f32x4 otl[4] = {}, oth[4] = {};
  char* const pw = Pl[w];

  auto STAGE = [&](int bb, int kb) {
    const int kv0 = kb * 64;
#pragma unroll
    for (int it = 0; it < 2; ++it) {
      const int s = it * 256 + t;
      const int r = s >> 3;
      const int sc = (s ^ r) & 7;  // inverse swizzle on the global source (G21)
      char* base = KV[bb] + (it * 256 + w * 64) * 16;
      GLDS(Kh + ((size_t)bh * L + kv0 + r) * 64 + sc * 8, base);
      GLDS(VhT + ((size_t)bh * 64 + r) * L + kv0 + sc * 8, base + 8192);
    }
  };

  auto TILE = [&](int bb, int kb, int diagkb, int qrow, const bf16x8* qf, float& m,
                  float& lsum, f32x4* ot) {
    const char* Kb = KV[bb];
    const char* Vb = KV[bb] + 8192;
    f32x4 st[4];
#pragma unroll
    for (int kf = 0; kf < 4; ++kf) {
      f32x4 c = {};
#pragma unroll
      for (int kc = 0; kc < 2; ++kc) {
        const int r = kf * 16 + lq;
        const int byte = (r * 128 + kc * 64 + lg * 16) ^ ((r & 7) << 4);
        c = MFMA16(*(const bf16x8*)(Kb + byte), qf[kc], c);
      }
      st[kf] = c;
    }
    if (kb == diagkb) {
      const int kv0 = kb * 64;
#pragma unroll
      for (int kf = 0; kf < 4; ++kf)
#pragma unroll
        for (int u = 0; u < 4; ++u)
          if (kv0 + kf * 16 + 4 * lg + u > qrow) st[kf][u] = -1e30f;
    }
    // row max (q = lq), reduce across lg groups
    float pmax = st[0][0];
#pragma unroll
    for (int kf = 0; kf < 4; ++kf)
#pragma unroll
      for (int u = 0; u < 4; ++u) pmax = fmaxf(pmax, st[kf][u]);
    pmax = fmaxf(pmax, __shfl_xor(pmax, 16, 64));
    pmax = fmaxf(pmax, __shfl_xor(pmax, 32, 64));
    // defer-max (T13): skip O/l rescale while max growth < 11
    if (!__all(pmax <= m + 11.0f)) {
      const float mn = fmaxf(m, pmax);
      const float c2 = __expf(m - mn);
      lsum *= c2;
#pragma unroll
      for (int df = 0; df < 4; ++df) ot[df] *= c2;
      m = mn;
    }
    float psum = 0.0f;
#pragma unroll
    for (int kf = 0; kf < 4; ++kf) {
      const float p0 = __expf(st[kf][0] - m);
      const float p1 = __expf(st[kf][1] - m);
      const float p2 = __expf(st[kf][2] - m);
      const float p3 = __expf(st[kf][3] - m);
      psum += (p0 + p1) + (p2 + p3);
      uint2 pk;
      pk.x = cvtpk_bf16(p0, p1);
      pk.y = cvtpk_bf16(p2, p3);
      const int byte = (lq * 128 + kf * 32 + lg * 8) ^ ((lq & 7) << 4);
      *(uint2*)(pw + byte) = pk;
    }
    psum += __shfl_xor(psum, 16, 64);
    psum += __shfl_xor(psum, 32, 64);
    lsum += psum;
    asm volatile("s_waitcnt lgkmcnt(0)" ::: "memory");
    // O^T[d][q] += V^T . P^T
#pragma unroll
    for (int df = 0; df < 4; ++df) {
#pragma unroll
      for (int kc = 0; kc < 2; ++kc) {
        const int r = df * 16 + lq;
        const int byte = (r * 128 + kc * 64 + lg * 16) ^ ((r & 7) << 4);
        const int pbyte = (lq * 128 + kc * 64 + lg * 16) ^ ((lq & 7) << 4);
        ot[df] = MFMA16(*(const bf16x8*)(Vb + byte), *(const bf16x8*)(pw + pbyte), ot[df]);
      }
    }
  };

  STAGE(0, 0);
  __syncthreads();
  int cur = 0;
  for (int kb = 0; kb < nt; ++kb) {
    if (kb + 1 < nt) STAGE(cur ^ 1, kb + 1);  // prefetch overlaps both tiles' compute
    TILE(cur, kb, hi, qhi, qfh, mh, lh, oth);
    if (kb <= lo) TILE(cur, kb, lo, qlo, qfl, ml, ll, otl);
    __syncthreads();
    cur ^= 1;
  }

  const int b = bh >> 4, h = bh & 15;
  {
    const float inv = 1.0f / lh;
#pragma unroll
    for (int df = 0; df < 4; ++df) {
      u16x4 o;
#pragma unroll
      for (int u = 0; u < 4; ++u) o[u] = f2bf(oth[df][u] * inv);
      *(u16x4*)(attn + ((size_t)b * L + qhi) * 1024 + h * 64 + df * 16 + 4 * lg) = o;
    }
  }
  {
    const float inv = 1.0f / ll;
#pragma unroll
    for (int df = 0; df < 4; ++df) {
      u16x4 o;
#pragma unroll
      for (int u = 0; u < 4; ++u) o[u] = f2bf(otl[df][u] * inv);
      *(u16x4*)(attn + ((size_t)b * L + qlo) * 1024 + h * 64 + df * 16 + 4 * lg) = o;
    }
  }
}

// ---------------------------------------------------------------- launcher
extern "C" void kernel_launch(void* const* d_in, const int* in_sizes, int n_in,
                              void* d_out, int out_size, void* d_ws, size_t ws_size,
                              hipStream_t stream) {
  const float* q = (const float*)d_in[0];
  const float* k = (const float*)d_in[1];
  const float* v = (const float*)d_in[2];
  const float* Wq = (const float*)d_in[3];
  const float* bq = (const float*)d_in[4];
  const float* Wk = (const float*)d_in[5];
  const float* bk = (const float*)d_in[6];
  const float* Wv = (const float*)d_in[7];
  const float* bv = (const float*)d_in[8];
  const float* Wo = (const float*)d_in[9];
  const float* bo = (const float*)d_in[10];

  char* ws = (char*)d_ws;
  const size_t MB = 1ull << 20;
  ushort_t* qb = (ushort_t*)(ws + 0 * MB);    // 16MB (later reused as attn)
  ushort_t* kb = (ushort_t*)(ws + 16 * MB);   // 16MB (later reused as VhT)
  ushort_t* vb = (ushort_t*)(ws + 32 * MB);   // 16MB
  ushort_t* Wqb = (ushort_t*)(ws + 48 * MB);  // 2MB
  ushort_t* Wkb = (ushort_t*)(ws + 50 * MB);  // 2MB
  ushort_t* Wvb = (ushort_t*)(ws + 52 * MB);  // 2MB
  ushort_t* Wob = (ushort_t*)(ws + 54 * MB);  // 2MB
  float2* rope = (float2*)(ws + 56 * MB);     // 512KB
  ushort_t* Qh = (ushort_t*)(ws + 57 * MB);   // 16MB
  ushort_t* Kh = (ushort_t*)(ws + 73 * MB);   // 16MB
  ushort_t* Vh = (ushort_t*)(ws + 89 * MB);   // 16MB (total 105MB)
  ushort_t* VhT = kb;    // alias: kb dead after K projection
  ushort_t* attnb = qb;  // alias: qb dead after Q projection

  cvt_qkv<<<dim3(4096, 3), 256, 0, stream>>>(q, k, v, qb, kb, vb);
  cvt_w<<<dim3(512, 4), 256, 0, stream>>>(Wq, Wk, Wv, Wo, Wqb, Wkb, Wvb, Wob);
  rope_table_k<<<256, 256, 0, stream>>>(rope);

  dim3 gg(8, 64);
  gemm_bt<1><<<gg, 256, 0, stream>>>(qb, Wqb, bq, Qh, rope, 0.125f);
  gemm_bt<1><<<gg, 256, 0, stream>>>(kb, Wkb, bk, Kh, rope, 1.0f);
  gemm_bt<2><<<gg, 256, 0, stream>>>(vb, Wvb, bv, Vh, rope, 1.0f);

  transpose_v<<<dim3(32, 64), 256, 0, stream>>>(Vh, VhT);

  attn_fwd<<<dim3(16, 64), 256, 0, stream>>>(Qh, Kh, VhT, attnb);

  gemm_bt<0><<<gg, 256, 0, stream>>>(attnb, Wob, bo, d_out, rope, 1.0f);

  (void)in_sizes; (void)n_in; (void)out_size; (void)ws_size;
}